// Round 11
// baseline (242.196 us; speedup 1.0000x reference)
//
#include <hip/hip_runtime.h>
#include <cstdint>
#include <cstddef>

using u16 = unsigned short;
using u32 = unsigned int;
using u64 = unsigned long long;

typedef short bf16x8 __attribute__((ext_vector_type(8)));
typedef float f32x4 __attribute__((ext_vector_type(4)));

constexpr int BATCH = 2;
constexpr int N0 = 8192;
constexpr int N1 = 4096;
constexpr int N2 = 2048;
constexpr int COUT = 128;
constexpr int KNB = 16;

__device__ __forceinline__ float bf2f(u16 v) { return __uint_as_float(((u32)v) << 16); }
__device__ __forceinline__ u16 f2bf(float f) {  // round-to-nearest-even
    u32 u = __float_as_uint(f);
    return (u16)((u + 0x7fffu + ((u >> 16) & 1u)) >> 16);
}
__device__ __forceinline__ void cvt8(const float* __restrict__ src, u16* __restrict__ dst, int e) {
    float t0[8];
    *(float4*)t0 = *(const float4*)(src + e);
    *(float4*)(t0 + 4) = *(const float4*)(src + e + 4);
    u16 o[8];
#pragma unroll
    for (int q = 0; q < 8; ++q) o[q] = f2bf(t0[q]);
    *(uint4*)(dst + e) = *(uint4*)o;
}

// Distances must match the np reference bit-exactly: no FMA contraction, sequential sum.
__device__ __forceinline__ float dist2s(float cx, float cy, float cz,
                                        float px, float py, float pz) {
#pragma clang fp contract(off)
    float dx = cx - px;
    float dy = cy - py;
    float dz = cz - pz;
    float s = dx * dx;
    s = s + dy * dy;
    s = s + dz * dz;
    return s;
}

// ---- DPP cross-lane helpers (VALU pipe, no LDS traffic) ----
template <int CTRL>
__device__ __forceinline__ u64 dpp64(u64 v) {
    int lo = (int)(u32)v, hi = (int)(u32)(v >> 32);
    int plo = __builtin_amdgcn_update_dpp(0, lo, CTRL, 0xF, 0xF, true);
    int phi = __builtin_amdgcn_update_dpp(0, hi, CTRL, 0xF, 0xF, true);
    return (((u64)(u32)phi) << 32) | (u32)plo;
}
// row_shr:1 with bound_ctrl=1: lane L gets lane L-1; lane 0 of each 16-row gets 0.
__device__ __forceinline__ u64 dpp_prev_u64(u64 v) { return dpp64<0x111>(v); }
// bitonic exchange partners: xor1=quad_perm 0xB1, xor2=quad_perm 0x4E, xor8=row_ror:8 (0x128).

// ---------------- KNN scan over candidates [base, base+cnt): one wave, TWO centers (ILP).
// Sorted-16 list in lanes 0..15 as u64 (d2_bits<<32)|idx — exact order + low-index tie-break.
// Candidate broadcast = 1 u32 shfl; cut = u32 distance (d<=cut ballot is a SUPERSET of
// exact u64 hits; exact compare in insert makes extras no-ops). Shift = DPP (VALU). ----------------
__device__ __forceinline__ void knn_scan(const float* __restrict__ P, int pstride,
                                         int c0row, int c1row, int base, int cnt,
                                         int lane, u64& rk0, u64& rk1) {
    const float* c0p = P + (size_t)c0row * pstride;
    const float* c1p = P + (size_t)c1row * pstride;
    float c0x = c0p[0], c0y = c0p[1], c0z = c0p[2];
    float c1x = c1p[0], c1y = c1p[1], c1z = c1p[2];

    u64 key0, key1;
    {   // warm start: bitonic-sort first 64 subset points (xor 1/2/8 via DPP)
        const float* pp = P + (size_t)(base + lane) * pstride;
        float px = pp[0], py = pp[1], pz = pp[2];
        u64 k0 = (((u64)__float_as_uint(dist2s(c0x, c0y, c0z, px, py, pz))) << 32) | (u32)(base + lane);
        u64 k1 = (((u64)__float_as_uint(dist2s(c1x, c1y, c1z, px, py, pz))) << 32) | (u32)(base + lane);
#pragma unroll
        for (int kk = 2; kk <= 64; kk <<= 1)
#pragma unroll
            for (int jj = kk >> 1; jj > 0; jj >>= 1) {
                u64 o0, o1;
                if (jj == 1)      { o0 = dpp64<0xB1>(k0);  o1 = dpp64<0xB1>(k1); }
                else if (jj == 2) { o0 = dpp64<0x4E>(k0);  o1 = dpp64<0x4E>(k1); }
                else if (jj == 8) { o0 = dpp64<0x128>(k0); o1 = dpp64<0x128>(k1); }
                else              { o0 = __shfl_xor(k0, jj, 64); o1 = __shfl_xor(k1, jj, 64); }
                bool keepmin = (((lane & jj) == 0) == ((lane & kk) == 0));
                k0 = keepmin ? ((o0 < k0) ? o0 : k0) : ((o0 > k0) ? o0 : k0);
                k1 = keepmin ? ((o1 < k1) ? o1 : k1) : ((o1 > k1) ? o1 : k1);
            }
        key0 = k0; key1 = k1;
    }
    u32 cut0 = __shfl((u32)(key0 >> 32), 15, 64);
    u32 cut1 = __shfl((u32)(key1 >> 32), 15, 64);

    int nstep = cnt >> 6;
    const float* pp = P + (size_t)(base + 64 + lane) * pstride;
    float pnx = pp[0], pny = pp[1], pnz = pp[2];
    for (int s = 1; s < nstep; ++s) {
        float px = pnx, py = pny, pz = pnz;
        int nx = (s + 1 < nstep) ? ((s + 1) << 6) : (s << 6);
        const float* np_ = P + (size_t)(base + nx + lane) * pstride;
        pnx = np_[0]; pny = np_[1]; pnz = np_[2];
        int sb = base + (s << 6);
        u32 d0 = __float_as_uint(dist2s(c0x, c0y, c0z, px, py, pz));
        u32 d1 = __float_as_uint(dist2s(c1x, c1y, c1z, px, py, pz));
        u64 ball0 = __ballot(d0 <= cut0);
        u64 ball1 = __ballot(d1 <= cut1);
        bool any0 = ball0 != 0, any1 = ball1 != 0;
        while (ball0 | ball1) {   // two independent chains -> ILP
            if (ball0) {
                int src = __ffsll((unsigned long long)ball0) - 1;
                ball0 &= ball0 - 1;
                u32 dn = __shfl(d0, src, 64);
                u64 nk = (((u64)dn) << 32) | (u32)(sb + src);
                u64 prev = dpp_prev_u64(key0);
                key0 = (nk < key0) ? ((nk < prev) ? prev : nk) : key0;
            }
            if (ball1) {
                int src = __ffsll((unsigned long long)ball1) - 1;
                ball1 &= ball1 - 1;
                u32 dn = __shfl(d1, src, 64);
                u64 nk = (((u64)dn) << 32) | (u32)(sb + src);
                u64 prev = dpp_prev_u64(key1);
                key1 = (nk < key1) ? ((nk < prev) ? prev : nk) : key1;
            }
        }
        if (any0) cut0 = __shfl((u32)(key0 >> 32), 15, 64);
        if (any1) cut1 = __shfl((u32)(key1 >> 32), 15, 64);
    }
    rk0 = key0; rk1 = key1;
}

// ---------------- dispatch 1: knn1 split-2 (2048 blk) + knn2 (512 blk) + prep (752 blk) ----------------
__global__ __launch_bounds__(256)
void knn_prep_kernel(const float* __restrict__ pos0, const float* __restrict__ ch0,
                     const float* __restrict__ W1, const float* __restrict__ W2,
                     const float* __restrict__ Wres,
                     int* __restrict__ knn1, int* __restrict__ knn2,
                     u16* __restrict__ ch0b, u16* __restrict__ W1b,
                     u16* __restrict__ W2b, u16* __restrict__ Wresb,
                     float* __restrict__ pos_out) {
    __shared__ u64 mk[2][2][2][16];   // [pair-in-block][half][center][rank]
    int blk = blockIdx.x, tid = threadIdx.x;
    int w = tid >> 6, lane = tid & 63;
    if (blk < 2048) {
        // knn1: 2 waves per center-pair, each scans a disjoint 4096-candidate half;
        // exact merge: global top-16 ⊆ union of per-half top-16s; full-u64 sort of the
        // 32-key union keeps exact order incl. tie-break.
        int pi = w >> 1, h = w & 1;
        int p = blk * 2 + pi;                  // 0..4095 center-pairs
        int batch = p >> 11, pj = p & 2047;
        const float* P = pos0 + (size_t)batch * N0 * 3;
        u64 key0, key1;
        knn_scan(P, 3, 4 * pj, 4 * pj + 2, h * 4096, 4096, lane, key0, key1);
        if (lane < 16) { mk[pi][h][0][lane] = key0; mk[pi][h][1][lane] = key1; }
        __syncthreads();
        if (h == 0) {   // waves 0 and 2 merge their pair's two centers
            int c = lane >> 5, l = lane & 31;
            u64 k = mk[pi][l >> 4][c][l & 15];
            // bitonic sort of 32 keys within each 32-lane group (all xor dists <= 16)
#pragma unroll
            for (int kk = 2; kk <= 32; kk <<= 1)
#pragma unroll
                for (int jj = kk >> 1; jj > 0; jj >>= 1) {
                    u64 o;
                    if (jj == 1)      o = dpp64<0xB1>(k);
                    else if (jj == 2) o = dpp64<0x4E>(k);
                    else if (jj == 8) o = dpp64<0x128>(k);
                    else              o = __shfl_xor(k, jj, 64);
                    bool keepmin = (((l & jj) == 0) == ((l & kk) == 0));
                    k = keepmin ? ((o < k) ? o : k) : ((o > k) ? o : k);
                }
            if (l < 16)
                knn1[((size_t)(batch * N1 + 2 * pj + c)) * KNB + l] = (int)(u32)k;
        }
    } else if (blk < 2560) {
        // knn2: one wave per center-pair, full 4096-candidate scan over level-1 rows (stride 6)
        int wave = (blk - 2048) * 4 + w;
        int batch = wave >> 10, pj = wave & 1023;
        const float* P = pos0 + (size_t)batch * N0 * 3;
        u64 key0, key1;
        knn_scan(P, 6, 4 * pj, 4 * pj + 2, 0, N1, lane, key0, key1);
        if (lane < 16) {
            knn2[((size_t)(batch * N2 + 2 * pj)) * KNB + lane] = (int)(u32)key0;
            knn2[((size_t)(batch * N2 + 2 * pj + 1)) * KNB + lane] = (int)(u32)key1;
        }
    } else if (blk < 3072) {          // ch0 -> bf16 (1,048,576 elems)
        cvt8(ch0, ch0b, ((blk - 2560) * 256 + tid) * 8);
    } else if (blk < 3136) {          // W1 -> bf16 (131,072)
        cvt8(W1, W1b, ((blk - 3072) * 256 + tid) * 8);
    } else if (blk < 3264) {          // W2 -> bf16 (262,144)
        cvt8(W2, W2b, ((blk - 3136) * 256 + tid) * 8);
    } else if (blk < 3296) {          // Wres[c][o] -> Wresb[o][c] bf16 (8192 elems)
        int t = (blk - 3264) * 256 + tid;
        int o = t >> 6, c = t & 63;
        Wresb[o * 64 + c] = f2bf(Wres[(size_t)c * COUT + o]);
    } else {                          // pos_out copy: 4096 rows (16 blocks)
        int t = (blk - 3296) * 256 + tid;
        int b = t >> 11, r = t & 2047;
        const float* s = pos0 + ((size_t)(b * N0 + r * 4)) * 3;
        float* d = pos_out + ((size_t)(b * N2 + r)) * 3;
        d[0] = s[0]; d[1] = s[1]; d[2] = s[2];
    }
}

// ---------------- dispatch 2: conv1 MFMA, M=16 per block (512 blocks) ----------------
__global__ __launch_bounds__(256)
void conv1_kernel(const u16* __restrict__ ch0b, const int* __restrict__ knn1,
                  const u16* __restrict__ W1b, const u16* __restrict__ Wresb,
                  const float* __restrict__ b1, const float* __restrict__ bres,
                  const float* __restrict__ g1, const float* __restrict__ be1,
                  u16* __restrict__ ch1b, u16* __restrict__ res1b) {
    __shared__ u16 As[16][72];        // 16 rows x 64 bf16, +8 pad
    __shared__ u16 Ws[128][72];       // 128 cols x 64 bf16, +8 pad
    __shared__ int knnr[16][16];
    __shared__ float red[16][4][2];
    __shared__ float cb[128], cg[128], cbe[128], cbr[128];

    int tid = threadIdx.x;
    int blk = blockIdx.x;             // 512 blocks
    int b = blk >> 8, g = blk & 255;
    int jbase = g * 16;

    if (tid < 128) { cb[tid] = b1[tid]; cg[tid] = g1[tid]; cbe[tid] = be1[tid]; cbr[tid] = bres[tid]; }
    {   // 256 knn ints, 1 per thread
        int r = tid >> 4, k = tid & 15;
        knnr[r][k] = knn1[((size_t)(b * N1 + jbase + r)) * KNB + k];
    }
    __syncthreads();

    int w = tid >> 6, lane = tid & 63, quad = lane >> 4, l15 = lane & 15;
    int wcol = w * 32;
    int ar = tid >> 4, ap = tid & 15;     // A staging: 16 rows x 16 chunks of 8B
    int wn = tid >> 1, wh = tid & 1;      // W staging: 128 cols x 2 halves of 64B

    f32x4 acc[2] = {{0,0,0,0},{0,0,0,0}};
    f32x4 racc[2] = {{0,0,0,0},{0,0,0,0}};

    // software pipeline: prefetch chunk 0
    uint2 aR = *((const uint2*)(ch0b + ((size_t)(b * N0 + knnr[ar][0])) * 64) + ap);
    uint4 wR[4];
    {
        const uint4* s4 = (const uint4*)(W1b + (size_t)wn * 1024 + wh * 32);
        wR[0] = s4[0]; wR[1] = s4[1]; wR[2] = s4[2]; wR[3] = s4[3];
    }
    for (int kn = 0; kn < 17; ++kn) {     // 16 neighbor chunks + 1 residual chunk
        *(uint2*)&As[ar][ap * 4] = aR;
        uint4* d4 = (uint4*)&Ws[wn][wh * 32];
        d4[0] = wR[0]; d4[1] = wR[1]; d4[2] = wR[2]; d4[3] = wR[3];
        __syncthreads();
        if (kn < 16) {  // prefetch next chunk (kn==15 -> residual sources)
            int nidx = (kn < 15) ? knnr[ar][kn + 1] : 2 * (jbase + ar);
            aR = *((const uint2*)(ch0b + ((size_t)(b * N0 + nidx)) * 64) + ap);
            const uint4* s4 = (kn < 15)
                ? (const uint4*)(W1b + (size_t)wn * 1024 + (kn + 1) * 64 + wh * 32)
                : (const uint4*)(Wresb + (size_t)wn * 64 + wh * 32);
            wR[0] = s4[0]; wR[1] = s4[1]; wR[2] = s4[2]; wR[3] = s4[3];
        }
        if (kn < 16) {
#pragma unroll
            for (int ks = 0; ks < 2; ++ks) {
                bf16x8 af = *(const bf16x8*)&As[l15][ks * 32 + quad * 8];
#pragma unroll
                for (int nt = 0; nt < 2; ++nt) {
                    bf16x8 bfr = *(const bf16x8*)&Ws[wcol + nt * 16 + l15][ks * 32 + quad * 8];
                    acc[nt] = __builtin_amdgcn_mfma_f32_16x16x32_bf16(af, bfr, acc[nt], 0, 0, 0);
                }
            }
        } else {
#pragma unroll
            for (int ks = 0; ks < 2; ++ks) {
                bf16x8 af = *(const bf16x8*)&As[l15][ks * 32 + quad * 8];
#pragma unroll
                for (int nt = 0; nt < 2; ++nt) {
                    bf16x8 bfr = *(const bf16x8*)&Ws[wcol + nt * 16 + l15][ks * 32 + quad * 8];
                    racc[nt] = __builtin_amdgcn_mfma_f32_16x16x32_bf16(af, bfr, racc[nt], 0, 0, 0);
                }
            }
        }
        __syncthreads();
    }

    // epilogue: bias + LN(+SiLU) on conv acc; bias on residual; both stored bf16
    float x[2][4], s[4] = {0,0,0,0}, ss[4] = {0,0,0,0};
#pragma unroll
    for (int reg = 0; reg < 4; ++reg)
#pragma unroll
        for (int nt = 0; nt < 2; ++nt) {
            int col = wcol + nt * 16 + l15;
            float v = acc[nt][reg] + cb[col];
            x[nt][reg] = v;
            s[reg] += v; ss[reg] += v * v;
        }
#pragma unroll
    for (int m = 1; m < 16; m <<= 1)
#pragma unroll
        for (int reg = 0; reg < 4; ++reg) {
            s[reg] += __shfl_xor(s[reg], m, 64);
            ss[reg] += __shfl_xor(ss[reg], m, 64);
        }
    if (l15 == 0) {
#pragma unroll
        for (int reg = 0; reg < 4; ++reg) {
            red[quad * 4 + reg][w][0] = s[reg];
            red[quad * 4 + reg][w][1] = ss[reg];
        }
    }
    __syncthreads();
    float mu[4], rs[4];
#pragma unroll
    for (int reg = 0; reg < 4; ++reg) {
        int row = quad * 4 + reg;
        float S = red[row][0][0] + red[row][1][0] + red[row][2][0] + red[row][3][0];
        float SS = red[row][0][1] + red[row][1][1] + red[row][2][1] + red[row][3][1];
        mu[reg] = S * (1.f / 128.f);
        float var = fmaxf(SS * (1.f / 128.f) - mu[reg] * mu[reg], 0.f);
        rs[reg] = 1.f / sqrtf(var + 1e-5f);
    }
#pragma unroll
    for (int nt = 0; nt < 2; ++nt)
#pragma unroll
        for (int reg = 0; reg < 4; ++reg) {
            int col = wcol + nt * 16 + l15;
            int row = quad * 4 + reg;
            size_t off = ((size_t)(b * N1 + jbase + row)) * COUT + col;
            float y = (x[nt][reg] - mu[reg]) * rs[reg] * cg[col] + cbe[col];
            ch1b[off] = f2bf(y / (1.f + __expf(-y)));
            res1b[off] = f2bf(racc[nt][reg] + cbr[col]);
        }
}

// ---------------- dispatch 3: conv2 MFMA K=2048, 512 threads (8 waves), M=16 ----------------
__global__ __launch_bounds__(512)
void conv2_kernel(const u16* __restrict__ ch1b, const int* __restrict__ knn2,
                  const u16* __restrict__ W2b, const float* __restrict__ b2,
                  const float* __restrict__ g2, const float* __restrict__ be2,
                  const u16* __restrict__ res1b, float* __restrict__ ch_out) {
    __shared__ u16 As[16][136];       // 16 rows x 128 bf16, +8 pad
    __shared__ u16 Ws[128][136];
    __shared__ int knnr[16][16];
    __shared__ float red[16][8][2];
    __shared__ float cb[128], cg[128], cbe[128];

    int tid = threadIdx.x;            // 0..511
    int b = blockIdx.x >> 7, g = blockIdx.x & 127;
    int ibase = g * 16;

    if (tid < 128) { cb[tid] = b2[tid]; cg[tid] = g2[tid]; cbe[tid] = be2[tid]; }
    if (tid < 256) {
        int r = tid >> 4, k = tid & 15;
        knnr[r][k] = knn2[((size_t)(b * N2 + ibase + r)) * KNB + k];
    }
    __syncthreads();

    int w = tid >> 6, lane = tid & 63, quad = lane >> 4, l15 = lane & 15;
    int wcol = w * 16;
    int ar = tid >> 5, ap = tid & 31;     // A staging: 16 rows x 32 chunks of 8B
    int wn = tid >> 2, wq = tid & 3;      // W staging: 128 cols x 4 chunks of 64B

    f32x4 acc = {0, 0, 0, 0};

    uint2 aR = *((const uint2*)(ch1b + ((size_t)(b * N1 + knnr[ar][0])) * COUT) + ap);
    uint4 wR[4];
    {
        const uint4* s4 = (const uint4*)(W2b + (size_t)wn * 2048 + wq * 32);
        wR[0] = s4[0]; wR[1] = s4[1]; wR[2] = s4[2]; wR[3] = s4[3];
    }
    for (int kn = 0; kn < 16; ++kn) {
        *(uint2*)&As[ar][ap * 4] = aR;
        uint4* d4 = (uint4*)&Ws[wn][wq * 32];
        d4[0] = wR[0]; d4[1] = wR[1]; d4[2] = wR[2]; d4[3] = wR[3];
        __syncthreads();
        if (kn < 15) {
            aR = *((const uint2*)(ch1b + ((size_t)(b * N1 + knnr[ar][kn + 1])) * COUT) + ap);
            const uint4* s4 = (const uint4*)(W2b + (size_t)wn * 2048 + (kn + 1) * 128 + wq * 32);
            wR[0] = s4[0]; wR[1] = s4[1]; wR[2] = s4[2]; wR[3] = s4[3];
        }
#pragma unroll
        for (int ks = 0; ks < 4; ++ks) {
            bf16x8 af = *(const bf16x8*)&As[l15][ks * 32 + quad * 8];
            bf16x8 bfr = *(const bf16x8*)&Ws[wcol + l15][ks * 32 + quad * 8];
            acc = __builtin_amdgcn_mfma_f32_16x16x32_bf16(af, bfr, acc, 0, 0, 0);
        }
        __syncthreads();
    }

    float x[4], s[4], ss[4];
#pragma unroll
    for (int reg = 0; reg < 4; ++reg) {
        int col = wcol + l15;
        float v = acc[reg] + cb[col];
        x[reg] = v; s[reg] = v; ss[reg] = v * v;
    }
#pragma unroll
    for (int m = 1; m < 16; m <<= 1)
#pragma unroll
        for (int reg = 0; reg < 4; ++reg) {
            s[reg] += __shfl_xor(s[reg], m, 64);
            ss[reg] += __shfl_xor(ss[reg], m, 64);
        }
    if (l15 == 0) {
#pragma unroll
        for (int reg = 0; reg < 4; ++reg) {
            red[quad * 4 + reg][w][0] = s[reg];
            red[quad * 4 + reg][w][1] = ss[reg];
        }
    }
    __syncthreads();
#pragma unroll
    for (int reg = 0; reg < 4; ++reg) {
        int row = quad * 4 + reg;
        float S = 0.f, SS = 0.f;
#pragma unroll
        for (int t = 0; t < 8; ++t) { S += red[row][t][0]; SS += red[row][t][1]; }
        float mu = S * (1.f / 128.f);
        float var = fmaxf(SS * (1.f / 128.f) - mu * mu, 0.f);
        float rs = 1.f / sqrtf(var + 1e-5f);
        int col = wcol + l15;
        int i = ibase + row;
        float y = (x[reg] - mu) * rs * cg[col] + cbe[col];
        float sl = y / (1.f + __expf(-y));
        float rv = bf2f(res1b[((size_t)(b * N1 + 2 * i)) * COUT + col]);
        ch_out[((size_t)(b * N2 + i)) * COUT + col] = sl + rv;
    }
}

extern "C" void kernel_launch(void* const* d_in, const int* in_sizes, int n_in,
                              void* d_out, int out_size, void* d_ws, size_t ws_size,
                              hipStream_t stream) {
    const float* pos0 = (const float*)d_in[0];
    const float* ch0  = (const float*)d_in[1];
    const float* W1   = (const float*)d_in[2];
    const float* b1   = (const float*)d_in[3];
    const float* Wres = (const float*)d_in[4];
    const float* bres = (const float*)d_in[5];
    const float* W2   = (const float*)d_in[6];
    const float* b2   = (const float*)d_in[7];
    const float* g1   = (const float*)d_in[8];
    const float* be1  = (const float*)d_in[9];
    const float* g2   = (const float*)d_in[10];
    const float* be2  = (const float*)d_in[11];
    float* out = (float*)d_out;

    char* ws = (char*)d_ws;
    int*  knn1  = (int*)(ws);                      // 524288
    int*  knn2  = (int*)(ws + 524288);             // 262144
    u16*  ch0b  = (u16*)(ws + 786432);             // 2097152
    u16*  W1b   = (u16*)(ws + 2883584);            // 262144
    u16*  W2b   = (u16*)(ws + 3145728);            // 524288
    u16*  Wresb = (u16*)(ws + 3670016);            // 16384
    u16*  ch1b  = (u16*)(ws + 3686400);            // 2097152
    u16*  res1b = (u16*)(ws + 5783552);            // 2097152  (total ~7.9 MB)

    float* pos_out = out;          // [2,2048,3] fp32
    float* ch_out  = out + 12288;  // [2,2048,128] fp32

    knn_prep_kernel<<<3312, 256, 0, stream>>>(pos0, ch0, W1, W2, Wres,
                                              knn1, knn2, ch0b, W1b, W2b, Wresb, pos_out);
    conv1_kernel<<<512, 256, 0, stream>>>(ch0b, knn1, W1b, Wresb, b1, bres, g1, be1, ch1b, res1b);
    conv2_kernel<<<256, 512, 0, stream>>>(ch1b, knn2, W2b, b2, g2, be2, res1b, ch_out);
}

// Round 12
// 223.463 us; speedup vs baseline: 1.0838x; 1.0838x over previous
//
#include <hip/hip_runtime.h>
#include <cstdint>
#include <cstddef>

using u16 = unsigned short;
using u32 = unsigned int;
using u64 = unsigned long long;

typedef short bf16x8 __attribute__((ext_vector_type(8)));
typedef float f32x4 __attribute__((ext_vector_type(4)));

constexpr int BATCH = 2;
constexpr int N0 = 8192;
constexpr int N1 = 4096;
constexpr int N2 = 2048;
constexpr int COUT = 128;
constexpr int KNB = 16;

__device__ __forceinline__ float bf2f(u16 v) { return __uint_as_float(((u32)v) << 16); }
__device__ __forceinline__ u16 f2bf(float f) {  // round-to-nearest-even
    u32 u = __float_as_uint(f);
    return (u16)((u + 0x7fffu + ((u >> 16) & 1u)) >> 16);
}
__device__ __forceinline__ void cvt8(const float* __restrict__ src, u16* __restrict__ dst, int e) {
    float t0[8];
    *(float4*)t0 = *(const float4*)(src + e);
    *(float4*)(t0 + 4) = *(const float4*)(src + e + 4);
    u16 o[8];
#pragma unroll
    for (int q = 0; q < 8; ++q) o[q] = f2bf(t0[q]);
    *(uint4*)(dst + e) = *(uint4*)o;
}

// Distances must match the np reference bit-exactly: no FMA contraction, sequential sum.
__device__ __forceinline__ float dist2s(float cx, float cy, float cz,
                                        float px, float py, float pz) {
#pragma clang fp contract(off)
    float dx = cx - px;
    float dy = cy - py;
    float dz = cz - pz;
    float s = dx * dx;
    s = s + dy * dy;
    s = s + dz * dz;
    return s;
}

// ---- DPP cross-lane helpers (VALU pipe, no LDS traffic) ----
template <int CTRL>
__device__ __forceinline__ u64 dpp64(u64 v) {
    int lo = (int)(u32)v, hi = (int)(u32)(v >> 32);
    int plo = __builtin_amdgcn_update_dpp(0, lo, CTRL, 0xF, 0xF, true);
    int phi = __builtin_amdgcn_update_dpp(0, hi, CTRL, 0xF, 0xF, true);
    return (((u64)(u32)phi) << 32) | (u32)plo;
}
// row_shr:1 with bound_ctrl=1: lane L gets lane L-1; lane 0 of each 16-row gets 0.
__device__ __forceinline__ u64 dpp_prev_u64(u64 v) { return dpp64<0x111>(v); }
// bitonic exchange partners: xor1=quad_perm 0xB1, xor2=quad_perm 0x4E, xor8=row_ror:8 (0x128).

// ---------------- KNN scan, one wave, TWO centers, 128 candidates/step (2 per lane).
// Sorted-16 list in lanes 0..15 as u64 (d2_bits<<32)|idx — exact order + low-index tie-break.
// Candidate broadcast = 1 u32 shfl; cut = u32 distance (d<=cut ballot is a SUPERSET of
// exact u64 hits; exact compare in insert makes extras no-ops). Shift = DPP (VALU). ----------------
__device__ __forceinline__ void knn_scan(const float* __restrict__ P, int pstride,
                                         int c0row, int c1row, int cnt,
                                         int lane, u64& rk0, u64& rk1) {
    const float* c0p = P + (size_t)c0row * pstride;
    const float* c1p = P + (size_t)c1row * pstride;
    float c0x = c0p[0], c0y = c0p[1], c0z = c0p[2];
    float c1x = c1p[0], c1y = c1p[1], c1z = c1p[2];

    u64 key0, key1;
    {   // warm start: bitonic-sort first 64 points (xor 1/2/8 via DPP)
        const float* pp = P + (size_t)lane * pstride;
        float px = pp[0], py = pp[1], pz = pp[2];
        u64 k0 = (((u64)__float_as_uint(dist2s(c0x, c0y, c0z, px, py, pz))) << 32) | (u32)lane;
        u64 k1 = (((u64)__float_as_uint(dist2s(c1x, c1y, c1z, px, py, pz))) << 32) | (u32)lane;
#pragma unroll
        for (int kk = 2; kk <= 64; kk <<= 1)
#pragma unroll
            for (int jj = kk >> 1; jj > 0; jj >>= 1) {
                u64 o0, o1;
                if (jj == 1)      { o0 = dpp64<0xB1>(k0);  o1 = dpp64<0xB1>(k1); }
                else if (jj == 2) { o0 = dpp64<0x4E>(k0);  o1 = dpp64<0x4E>(k1); }
                else if (jj == 8) { o0 = dpp64<0x128>(k0); o1 = dpp64<0x128>(k1); }
                else              { o0 = __shfl_xor(k0, jj, 64); o1 = __shfl_xor(k1, jj, 64); }
                bool keepmin = (((lane & jj) == 0) == ((lane & kk) == 0));
                k0 = keepmin ? ((o0 < k0) ? o0 : k0) : ((o0 > k0) ? o0 : k0);
                k1 = keepmin ? ((o1 < k1) ? o1 : k1) : ((o1 > k1) ? o1 : k1);
            }
        key0 = k0; key1 = k1;
    }
    u32 cut0 = __shfl((u32)(key0 >> 32), 15, 64);
    u32 cut1 = __shfl((u32)(key1 >> 32), 15, 64);

    {   // half-step: candidates [64,128), one per lane
        const float* pp = P + (size_t)(64 + lane) * pstride;
        float px = pp[0], py = pp[1], pz = pp[2];
        u32 d0 = __float_as_uint(dist2s(c0x, c0y, c0z, px, py, pz));
        u32 d1 = __float_as_uint(dist2s(c1x, c1y, c1z, px, py, pz));
        u64 ball0 = __ballot(d0 <= cut0);
        u64 ball1 = __ballot(d1 <= cut1);
        bool any0 = ball0 != 0, any1 = ball1 != 0;
        while (ball0 | ball1) {
            if (ball0) {
                int src = __ffsll((unsigned long long)ball0) - 1;
                ball0 &= ball0 - 1;
                u64 nk = (((u64)__shfl(d0, src, 64)) << 32) | (u32)(64 + src);
                u64 prev = dpp_prev_u64(key0);
                key0 = (nk < key0) ? ((nk < prev) ? prev : nk) : key0;
            }
            if (ball1) {
                int src = __ffsll((unsigned long long)ball1) - 1;
                ball1 &= ball1 - 1;
                u64 nk = (((u64)__shfl(d1, src, 64)) << 32) | (u32)(64 + src);
                u64 prev = dpp_prev_u64(key1);
                key1 = (nk < key1) ? ((nk < prev) ? prev : nk) : key1;
            }
        }
        if (any0) cut0 = __shfl((u32)(key0 >> 32), 15, 64);
        if (any1) cut1 = __shfl((u32)(key1 >> 32), 15, 64);
    }

    // main loop: 128 candidates/step (2 per lane), starting at 128
    int nstep = (cnt - 128) >> 7;
    const float* pa = P + (size_t)(128 + 2 * lane) * pstride;
    float ax = pa[0], ay = pa[1], az = pa[2];
    float bx = pa[pstride], by = pa[pstride + 1], bz = pa[pstride + 2];
    for (int s = 0; s < nstep; ++s) {
        float cax = ax, cay = ay, caz = az, cbx = bx, cby = by, cbz = bz;
        int nxt = (s + 1 < nstep) ? (s + 1) : s;
        const float* pn = P + (size_t)(128 + (nxt << 7) + 2 * lane) * pstride;
        ax = pn[0]; ay = pn[1]; az = pn[2];
        bx = pn[pstride]; by = pn[pstride + 1]; bz = pn[pstride + 2];
        int sb = 128 + (s << 7);
        u32 da0 = __float_as_uint(dist2s(c0x, c0y, c0z, cax, cay, caz));
        u32 da1 = __float_as_uint(dist2s(c1x, c1y, c1z, cax, cay, caz));
        u32 db0 = __float_as_uint(dist2s(c0x, c0y, c0z, cbx, cby, cbz));
        u32 db1 = __float_as_uint(dist2s(c1x, c1y, c1z, cbx, cby, cbz));
        u64 ba0 = __ballot(da0 <= cut0);
        u64 bb0 = __ballot(db0 <= cut0);
        u64 ba1 = __ballot(da1 <= cut1);
        u64 bb1 = __ballot(db1 <= cut1);
        bool any0 = (ba0 | bb0) != 0, any1 = (ba1 | bb1) != 0;
        while (ba0 | bb0 | ba1 | bb1) {   // two independent key chains, 4 ballot streams
            if (ba0) {
                int src = __ffsll((unsigned long long)ba0) - 1;
                ba0 &= ba0 - 1;
                u64 nk = (((u64)__shfl(da0, src, 64)) << 32) | (u32)(sb + 2 * src);
                u64 prev = dpp_prev_u64(key0);
                key0 = (nk < key0) ? ((nk < prev) ? prev : nk) : key0;
            }
            if (ba1) {
                int src = __ffsll((unsigned long long)ba1) - 1;
                ba1 &= ba1 - 1;
                u64 nk = (((u64)__shfl(da1, src, 64)) << 32) | (u32)(sb + 2 * src);
                u64 prev = dpp_prev_u64(key1);
                key1 = (nk < key1) ? ((nk < prev) ? prev : nk) : key1;
            }
            if (bb0) {
                int src = __ffsll((unsigned long long)bb0) - 1;
                bb0 &= bb0 - 1;
                u64 nk = (((u64)__shfl(db0, src, 64)) << 32) | (u32)(sb + 2 * src + 1);
                u64 prev = dpp_prev_u64(key0);
                key0 = (nk < key0) ? ((nk < prev) ? prev : nk) : key0;
            }
            if (bb1) {
                int src = __ffsll((unsigned long long)bb1) - 1;
                bb1 &= bb1 - 1;
                u64 nk = (((u64)__shfl(db1, src, 64)) << 32) | (u32)(sb + 2 * src + 1);
                u64 prev = dpp_prev_u64(key1);
                key1 = (nk < key1) ? ((nk < prev) ? prev : nk) : key1;
            }
        }
        if (any0) cut0 = __shfl((u32)(key0 >> 32), 15, 64);
        if (any1) cut1 = __shfl((u32)(key1 >> 32), 15, 64);
    }
    rk0 = key0; rk1 = key1;
}

// ---------------- dispatch 1: knn1 (1024 blk) + knn2 (512 blk) + prep (752 blk) ----------------
__global__ __launch_bounds__(256)
void knn_prep_kernel(const float* __restrict__ pos0, const float* __restrict__ ch0,
                     const float* __restrict__ W1, const float* __restrict__ W2,
                     const float* __restrict__ Wres,
                     int* __restrict__ knn1, int* __restrict__ knn2,
                     u16* __restrict__ ch0b, u16* __restrict__ W1b,
                     u16* __restrict__ W2b, u16* __restrict__ Wresb,
                     float* __restrict__ pos_out) {
    int blk = blockIdx.x, tid = threadIdx.x;
    int w = tid >> 6, lane = tid & 63;
    if (blk < 1024) {
        // knn1: one wave per center-pair, full 8192-candidate scan (stride 3 floats)
        int wave = blk * 4 + w;
        int batch = wave >> 11, pj = wave & 2047;
        const float* P = pos0 + (size_t)batch * N0 * 3;
        u64 key0, key1;
        knn_scan(P, 3, 4 * pj, 4 * pj + 2, N0, lane, key0, key1);
        if (lane < 16) {
            knn1[((size_t)(batch * N1 + 2 * pj)) * KNB + lane] = (int)(u32)key0;
            knn1[((size_t)(batch * N1 + 2 * pj + 1)) * KNB + lane] = (int)(u32)key1;
        }
    } else if (blk < 1536) {
        // knn2: one wave per center-pair, full 4096-candidate scan over level-1 rows (stride 6)
        int wave = (blk - 1024) * 4 + w;
        int batch = wave >> 10, pj = wave & 1023;
        const float* P = pos0 + (size_t)batch * N0 * 3;
        u64 key0, key1;
        knn_scan(P, 6, 4 * pj, 4 * pj + 2, N1, lane, key0, key1);
        if (lane < 16) {
            knn2[((size_t)(batch * N2 + 2 * pj)) * KNB + lane] = (int)(u32)key0;
            knn2[((size_t)(batch * N2 + 2 * pj + 1)) * KNB + lane] = (int)(u32)key1;
        }
    } else if (blk < 2048) {          // ch0 -> bf16 (1,048,576 elems)
        cvt8(ch0, ch0b, ((blk - 1536) * 256 + tid) * 8);
    } else if (blk < 2112) {          // W1 -> bf16 (131,072)
        cvt8(W1, W1b, ((blk - 2048) * 256 + tid) * 8);
    } else if (blk < 2240) {          // W2 -> bf16 (262,144)
        cvt8(W2, W2b, ((blk - 2112) * 256 + tid) * 8);
    } else if (blk < 2272) {          // Wres[c][o] -> Wresb[o][c] bf16 (8192 elems)
        int t = (blk - 2240) * 256 + tid;
        int o = t >> 6, c = t & 63;
        Wresb[o * 64 + c] = f2bf(Wres[(size_t)c * COUT + o]);
    } else {                          // pos_out copy: 4096 rows (16 blocks)
        int t = (blk - 2272) * 256 + tid;
        int b = t >> 11, r = t & 2047;
        const float* s = pos0 + ((size_t)(b * N0 + r * 4)) * 3;
        float* d = pos_out + ((size_t)(b * N2 + r)) * 3;
        d[0] = s[0]; d[1] = s[1]; d[2] = s[2];
    }
}

// ---------------- dispatch 2: conv1 MFMA, M=16 per block (512 blocks) ----------------
__global__ __launch_bounds__(256)
void conv1_kernel(const u16* __restrict__ ch0b, const int* __restrict__ knn1,
                  const u16* __restrict__ W1b, const u16* __restrict__ Wresb,
                  const float* __restrict__ b1, const float* __restrict__ bres,
                  const float* __restrict__ g1, const float* __restrict__ be1,
                  u16* __restrict__ ch1b, u16* __restrict__ res1b) {
    __shared__ u16 As[16][72];        // 16 rows x 64 bf16, +8 pad
    __shared__ u16 Ws[128][72];       // 128 cols x 64 bf16, +8 pad
    __shared__ int knnr[16][16];
    __shared__ float red[16][4][2];
    __shared__ float cb[128], cg[128], cbe[128], cbr[128];

    int tid = threadIdx.x;
    int blk = blockIdx.x;             // 512 blocks
    int b = blk >> 8, g = blk & 255;
    int jbase = g * 16;

    if (tid < 128) { cb[tid] = b1[tid]; cg[tid] = g1[tid]; cbe[tid] = be1[tid]; cbr[tid] = bres[tid]; }
    {   // 256 knn ints, 1 per thread
        int r = tid >> 4, k = tid & 15;
        knnr[r][k] = knn1[((size_t)(b * N1 + jbase + r)) * KNB + k];
    }
    __syncthreads();

    int w = tid >> 6, lane = tid & 63, quad = lane >> 4, l15 = lane & 15;
    int wcol = w * 32;
    int ar = tid >> 4, ap = tid & 15;     // A staging: 16 rows x 16 chunks of 8B
    int wn = tid >> 1, wh = tid & 1;      // W staging: 128 cols x 2 halves of 64B

    f32x4 acc[2] = {{0,0,0,0},{0,0,0,0}};
    f32x4 racc[2] = {{0,0,0,0},{0,0,0,0}};

    // software pipeline: prefetch chunk 0
    uint2 aR = *((const uint2*)(ch0b + ((size_t)(b * N0 + knnr[ar][0])) * 64) + ap);
    uint4 wR[4];
    {
        const uint4* s4 = (const uint4*)(W1b + (size_t)wn * 1024 + wh * 32);
        wR[0] = s4[0]; wR[1] = s4[1]; wR[2] = s4[2]; wR[3] = s4[3];
    }
    for (int kn = 0; kn < 17; ++kn) {     // 16 neighbor chunks + 1 residual chunk
        *(uint2*)&As[ar][ap * 4] = aR;
        uint4* d4 = (uint4*)&Ws[wn][wh * 32];
        d4[0] = wR[0]; d4[1] = wR[1]; d4[2] = wR[2]; d4[3] = wR[3];
        __syncthreads();
        if (kn < 16) {  // prefetch next chunk (kn==15 -> residual sources)
            int nidx = (kn < 15) ? knnr[ar][kn + 1] : 2 * (jbase + ar);
            aR = *((const uint2*)(ch0b + ((size_t)(b * N0 + nidx)) * 64) + ap);
            const uint4* s4 = (kn < 15)
                ? (const uint4*)(W1b + (size_t)wn * 1024 + (kn + 1) * 64 + wh * 32)
                : (const uint4*)(Wresb + (size_t)wn * 64 + wh * 32);
            wR[0] = s4[0]; wR[1] = s4[1]; wR[2] = s4[2]; wR[3] = s4[3];
        }
        if (kn < 16) {
#pragma unroll
            for (int ks = 0; ks < 2; ++ks) {
                bf16x8 af = *(const bf16x8*)&As[l15][ks * 32 + quad * 8];
#pragma unroll
                for (int nt = 0; nt < 2; ++nt) {
                    bf16x8 bfr = *(const bf16x8*)&Ws[wcol + nt * 16 + l15][ks * 32 + quad * 8];
                    acc[nt] = __builtin_amdgcn_mfma_f32_16x16x32_bf16(af, bfr, acc[nt], 0, 0, 0);
                }
            }
        } else {
#pragma unroll
            for (int ks = 0; ks < 2; ++ks) {
                bf16x8 af = *(const bf16x8*)&As[l15][ks * 32 + quad * 8];
#pragma unroll
                for (int nt = 0; nt < 2; ++nt) {
                    bf16x8 bfr = *(const bf16x8*)&Ws[wcol + nt * 16 + l15][ks * 32 + quad * 8];
                    racc[nt] = __builtin_amdgcn_mfma_f32_16x16x32_bf16(af, bfr, racc[nt], 0, 0, 0);
                }
            }
        }
        __syncthreads();
    }

    // epilogue: bias + LN(+SiLU) on conv acc; bias on residual; both stored bf16
    float x[2][4], s[4] = {0,0,0,0}, ss[4] = {0,0,0,0};
#pragma unroll
    for (int reg = 0; reg < 4; ++reg)
#pragma unroll
        for (int nt = 0; nt < 2; ++nt) {
            int col = wcol + nt * 16 + l15;
            float v = acc[nt][reg] + cb[col];
            x[nt][reg] = v;
            s[reg] += v; ss[reg] += v * v;
        }
#pragma unroll
    for (int m = 1; m < 16; m <<= 1)
#pragma unroll
        for (int reg = 0; reg < 4; ++reg) {
            s[reg] += __shfl_xor(s[reg], m, 64);
            ss[reg] += __shfl_xor(ss[reg], m, 64);
        }
    if (l15 == 0) {
#pragma unroll
        for (int reg = 0; reg < 4; ++reg) {
            red[quad * 4 + reg][w][0] = s[reg];
            red[quad * 4 + reg][w][1] = ss[reg];
        }
    }
    __syncthreads();
    float mu[4], rs[4];
#pragma unroll
    for (int reg = 0; reg < 4; ++reg) {
        int row = quad * 4 + reg;
        float S = red[row][0][0] + red[row][1][0] + red[row][2][0] + red[row][3][0];
        float SS = red[row][0][1] + red[row][1][1] + red[row][2][1] + red[row][3][1];
        mu[reg] = S * (1.f / 128.f);
        float var = fmaxf(SS * (1.f / 128.f) - mu[reg] * mu[reg], 0.f);
        rs[reg] = 1.f / sqrtf(var + 1e-5f);
    }
#pragma unroll
    for (int nt = 0; nt < 2; ++nt)
#pragma unroll
        for (int reg = 0; reg < 4; ++reg) {
            int col = wcol + nt * 16 + l15;
            int row = quad * 4 + reg;
            size_t off = ((size_t)(b * N1 + jbase + row)) * COUT + col;
            float y = (x[nt][reg] - mu[reg]) * rs[reg] * cg[col] + cbe[col];
            ch1b[off] = f2bf(y / (1.f + __expf(-y)));
            res1b[off] = f2bf(racc[nt][reg] + cbr[col]);
        }
}

// ---------------- dispatch 3: conv2 MFMA K=2048, 512 threads (8 waves), M=16 ----------------
__global__ __launch_bounds__(512)
void conv2_kernel(const u16* __restrict__ ch1b, const int* __restrict__ knn2,
                  const u16* __restrict__ W2b, const float* __restrict__ b2,
                  const float* __restrict__ g2, const float* __restrict__ be2,
                  const u16* __restrict__ res1b, float* __restrict__ ch_out) {
    __shared__ u16 As[16][136];       // 16 rows x 128 bf16, +8 pad
    __shared__ u16 Ws[128][136];
    __shared__ int knnr[16][16];
    __shared__ float red[16][8][2];
    __shared__ float cb[128], cg[128], cbe[128];

    int tid = threadIdx.x;            // 0..511
    int b = blockIdx.x >> 7, g = blockIdx.x & 127;
    int ibase = g * 16;

    if (tid < 128) { cb[tid] = b2[tid]; cg[tid] = g2[tid]; cbe[tid] = be2[tid]; }
    if (tid < 256) {
        int r = tid >> 4, k = tid & 15;
        knnr[r][k] = knn2[((size_t)(b * N2 + ibase + r)) * KNB + k];
    }
    __syncthreads();

    int w = tid >> 6, lane = tid & 63, quad = lane >> 4, l15 = lane & 15;
    int wcol = w * 16;
    int ar = tid >> 5, ap = tid & 31;     // A staging: 16 rows x 32 chunks of 8B
    int wn = tid >> 2, wq = tid & 3;      // W staging: 128 cols x 4 chunks of 64B

    f32x4 acc = {0, 0, 0, 0};

    uint2 aR = *((const uint2*)(ch1b + ((size_t)(b * N1 + knnr[ar][0])) * COUT) + ap);
    uint4 wR[4];
    {
        const uint4* s4 = (const uint4*)(W2b + (size_t)wn * 2048 + wq * 32);
        wR[0] = s4[0]; wR[1] = s4[1]; wR[2] = s4[2]; wR[3] = s4[3];
    }
    for (int kn = 0; kn < 16; ++kn) {
        *(uint2*)&As[ar][ap * 4] = aR;
        uint4* d4 = (uint4*)&Ws[wn][wq * 32];
        d4[0] = wR[0]; d4[1] = wR[1]; d4[2] = wR[2]; d4[3] = wR[3];
        __syncthreads();
        if (kn < 15) {
            aR = *((const uint2*)(ch1b + ((size_t)(b * N1 + knnr[ar][kn + 1])) * COUT) + ap);
            const uint4* s4 = (const uint4*)(W2b + (size_t)wn * 2048 + (kn + 1) * 128 + wq * 32);
            wR[0] = s4[0]; wR[1] = s4[1]; wR[2] = s4[2]; wR[3] = s4[3];
        }
#pragma unroll
        for (int ks = 0; ks < 4; ++ks) {
            bf16x8 af = *(const bf16x8*)&As[l15][ks * 32 + quad * 8];
            bf16x8 bfr = *(const bf16x8*)&Ws[wcol + l15][ks * 32 + quad * 8];
            acc = __builtin_amdgcn_mfma_f32_16x16x32_bf16(af, bfr, acc, 0, 0, 0);
        }
        __syncthreads();
    }

    float x[4], s[4], ss[4];
#pragma unroll
    for (int reg = 0; reg < 4; ++reg) {
        int col = wcol + l15;
        float v = acc[reg] + cb[col];
        x[reg] = v; s[reg] = v; ss[reg] = v * v;
    }
#pragma unroll
    for (int m = 1; m < 16; m <<= 1)
#pragma unroll
        for (int reg = 0; reg < 4; ++reg) {
            s[reg] += __shfl_xor(s[reg], m, 64);
            ss[reg] += __shfl_xor(ss[reg], m, 64);
        }
    if (l15 == 0) {
#pragma unroll
        for (int reg = 0; reg < 4; ++reg) {
            red[quad * 4 + reg][w][0] = s[reg];
            red[quad * 4 + reg][w][1] = ss[reg];
        }
    }
    __syncthreads();
#pragma unroll
    for (int reg = 0; reg < 4; ++reg) {
        int row = quad * 4 + reg;
        float S = 0.f, SS = 0.f;
#pragma unroll
        for (int t = 0; t < 8; ++t) { S += red[row][t][0]; SS += red[row][t][1]; }
        float mu = S * (1.f / 128.f);
        float var = fmaxf(SS * (1.f / 128.f) - mu * mu, 0.f);
        float rs = 1.f / sqrtf(var + 1e-5f);
        int col = wcol + l15;
        int i = ibase + row;
        float y = (x[reg] - mu) * rs * cg[col] + cbe[col];
        float sl = y / (1.f + __expf(-y));
        float rv = bf2f(res1b[((size_t)(b * N1 + 2 * i)) * COUT + col]);
        ch_out[((size_t)(b * N2 + i)) * COUT + col] = sl + rv;
    }
}

extern "C" void kernel_launch(void* const* d_in, const int* in_sizes, int n_in,
                              void* d_out, int out_size, void* d_ws, size_t ws_size,
                              hipStream_t stream) {
    const float* pos0 = (const float*)d_in[0];
    const float* ch0  = (const float*)d_in[1];
    const float* W1   = (const float*)d_in[2];
    const float* b1   = (const float*)d_in[3];
    const float* Wres = (const float*)d_in[4];
    const float* bres = (const float*)d_in[5];
    const float* W2   = (const float*)d_in[6];
    const float* b2   = (const float*)d_in[7];
    const float* g1   = (const float*)d_in[8];
    const float* be1  = (const float*)d_in[9];
    const float* g2   = (const float*)d_in[10];
    const float* be2  = (const float*)d_in[11];
    float* out = (float*)d_out;

    char* ws = (char*)d_ws;
    int*  knn1  = (int*)(ws);                      // 524288
    int*  knn2  = (int*)(ws + 524288);             // 262144
    u16*  ch0b  = (u16*)(ws + 786432);             // 2097152
    u16*  W1b   = (u16*)(ws + 2883584);            // 262144
    u16*  W2b   = (u16*)(ws + 3145728);            // 524288
    u16*  Wresb = (u16*)(ws + 3670016);            // 16384
    u16*  ch1b  = (u16*)(ws + 3686400);            // 2097152
    u16*  res1b = (u16*)(ws + 5783552);            // 2097152  (total ~7.9 MB)

    float* pos_out = out;          // [2,2048,3] fp32
    float* ch_out  = out + 12288;  // [2,2048,128] fp32

    knn_prep_kernel<<<2288, 256, 0, stream>>>(pos0, ch0, W1, W2, Wres,
                                              knn1, knn2, ch0b, W1b, W2b, Wresb, pos_out);
    conv1_kernel<<<512, 256, 0, stream>>>(ch0b, knn1, W1b, Wresb, b1, bres, g1, be1, ch1b, res1b);
    conv2_kernel<<<256, 512, 0, stream>>>(ch1b, knn2, W2b, b2, g2, be2, res1b, ch_out);
}